// Round 8
// baseline (475.434 us; speedup 1.0000x reference)
//
#include <hip/hip_runtime.h>
#include <hip/hip_cooperative_groups.h>

namespace cg = cooperative_groups;

#define T_ 15
#define CIN 6
#define H0 160
#define W0 160
#define C1_ 128
#define C2_ 256
#define HP 83            // padded pooled grid (83x83)
#define H2 82            // conv2 output (82x82)
#define NPIX (H0*W0)     // 25600
#define NIN (CIN*NPIX)   // 153600
#define NPOS (H2*H2)     // 6724
#define NS (T_*C2_*NPOS) // 25,820,160 elements per s/v output
#define THR1 10.0f
#define THR2 1.0f
#define NF1 2048
#define NF2 2048

// ===========================================================================
// Cooperative mega-kernel: phases A(prep+fillA) -> B(conv1+fillB) -> C(pool)
// -> D(conv2+inhibition+scatter). Phase bodies are verbatim ports of the
// validated kernels (bit-identical arithmetic). 3 grid syncs.
__global__ __launch_bounds__(256, 4) void k_coop(
    const float* __restrict__ inp, const float* __restrict__ w1,
    const float* __restrict__ w2, unsigned int* __restrict__ maskg,
    float* __restrict__ w1T, float* __restrict__ w2T,
    unsigned char* __restrict__ fst1, unsigned char* __restrict__ win_t,
    unsigned char* __restrict__ win_ch, float* __restrict__ vals,
    int* __restrict__ nsp_arr, int* __restrict__ ow_arr,
    unsigned int* __restrict__ bigbits, float* __restrict__ s_out,
    float* __restrict__ v_out, uint4* __restrict__ fill_dst, size_t n16) {
    __shared__ unsigned char tft[CIN * 20 * 20];
    __shared__ int cnt[16 * 256];
    cg::grid_group gg = cg::this_grid();
    int b = blockIdx.x, tid = threadIdx.x;
    int nb = gridDim.x;
    int nwaves = nb * 4;
    int wid = b * 4 + (tid >> 6);
    int lane = tid & 63;
    const uint4 z4 = make_uint4(0u, 0u, 0u, 0u);
    size_t nA = n16 / 2;

    // ---------------- Phase A: prep + fill chunk A ----------------
    for (int u = b; u < 687; u += nb) {
        if (u < 100) {
            __syncthreads();                       // WAR guard on tft reuse
            int ty0 = (u / 10) * 16, tx0 = (u % 10) * 16;
            for (int i = tid; i < CIN * 400; i += 256) {
                int ci = i / 400, rem = i % 400;
                int ly = rem / 20, lx = rem % 20;
                int y = ty0 + ly - 2, x = tx0 + lx - 2;
                unsigned char tv = 15;
                if ((unsigned)y < (unsigned)H0 && (unsigned)x < (unsigned)W0) {
                    float c = 0.f;
                    int base = ci * NPIX + y * W0 + x;
#pragma unroll
                    for (int t = 0; t < T_; t++) c += inp[(size_t)t * NIN + base];
                    tv = (unsigned char)(15 - (int)(c + 0.5f));
                }
                tft[i] = tv;
            }
            __syncthreads();
            int tyl = tid >> 4, txl = tid & 15;
            int pix = (ty0 + tyl) * W0 + (tx0 + txl);
            int* col = cnt + tid;   // private column: bank = tid%32, conflict-free
#pragma unroll
            for (int w = 0; w < 5; w++) {
                int j0 = w * 32, j1 = (w == 4) ? 150 : (j0 + 32);
#pragma unroll
                for (int q = 0; q < 16; q++) col[q * 256] = 0;
#pragma unroll 32
                for (int j = j0; j < j1; j++) {
                    int ci = j / 25, r = j % 25, ky = r / 5, kx = r % 5;
                    int tfv = tft[ci * 400 + (tyl + ky) * 20 + (txl + kx)];
                    col[tfv * 256] |= 1u << (j & 31);   // slot 15 = trash
                }
#pragma unroll
                for (int t = 0; t < 15; t++)
                    maskg[(size_t)(t * 5 + w) * NPIX + pix] = (unsigned)col[t * 256];
            }
        } else if (u < 175) {
            int idx = (u - 100) * 256 + tid;      // < 19200
            int j = idx >> 7, c = idx & 127;
            w1T[idx] = w1[c * 150 + j];
        } else {
            int idx = (u - 175) * 256 + tid;      // < 131072
            int o = idx & 255, kcc = idx >> 8;
            int cc = kcc & 127, k = kcc >> 7;
            w2T[idx] = w2[o * 512 + cc * 4 + k];
        }
    }
    if (b == 0 && tid == 0) *bigbits = 0u;
    for (size_t i = (size_t)b * 256 + tid; i < nA; i += (size_t)nb * 256)
        fill_dst[i] = z4;
    gg.sync();

    // ---------------- Phase B: conv1 first-crossing + fill chunk B ----------
    {
        const float* wb = w1T + 2 * lane;
        for (int pix = wid; pix < NPIX; pix += nwaves) {
            float v0 = 0.f, v1 = 0.f;
            int f0 = 15, f1 = 15;
            for (int t = 0; t < 15; ++t) {
                float b0 = 0.f, b1 = 0.f;
#pragma unroll
                for (int w = 0; w < 5; ++w) {
                    unsigned int m = maskg[(size_t)(t * 5 + w) * NPIX + pix];
                    int base = w * 32;
                    while (m) {
                        int j = base + __builtin_ctz(m);
                        m &= m - 1;
                        float2 ww = *(const float2*)(wb + j * C1_);
                        b0 += ww.x; b1 += ww.y;
                    }
                }
                v0 += b0; v1 += b1;
                f0 = (f0 == 15 && v0 >= THR1) ? t : f0;
                f1 = (f1 == 15 && v1 >= THR1) ? t : f1;
                if (__all((f0 < 15) & (f1 < 15))) break;
            }
            *(uchar2*)(fst1 + (size_t)pix * C1_ + 2 * lane) =
                make_uchar2((unsigned char)f0, (unsigned char)f1);
        }
    }
    for (size_t i = nA + (size_t)b * 256 + tid; i < n16; i += (size_t)nb * 256)
        fill_dst[i] = z4;
    gg.sync();

    // ---------------- Phase C: pool-min + pointwise inhibition ----------------
    for (int pos = wid; pos < HP * HP; pos += nwaves) {
        int py = pos / HP, px = pos % HP;
        if (py == 0 || py == HP - 1 || px == 0 || px == HP - 1) {
            if (lane == 0) { win_t[pos] = 15; win_ch[pos] = 0; }
            continue;
        }
        int y0 = 2 * py - 3, x0 = 2 * px - 3;
        int m0 = 15, m1 = 15;
#pragma unroll
        for (int dy = 0; dy < 2; dy++) {
            int y = y0 + dy;
            if ((unsigned)y < (unsigned)H0) {
#pragma unroll
                for (int dx = 0; dx < 2; dx++) {
                    int x = x0 + dx;
                    if ((unsigned)x < (unsigned)W0) {
                        uchar2 f = *(const uchar2*)(fst1 + (size_t)(y * W0 + x) * C1_ + 2 * lane);
                        m0 = f.x < m0 ? f.x : m0;
                        m1 = f.y < m1 ? f.y : m1;
                    }
                }
            }
        }
        int k0 = (m0 << 8) | (2 * lane);
        int k1 = (m1 << 8) | (2 * lane + 1);
        int key = k0 < k1 ? k0 : k1;
#pragma unroll
        for (int off = 32; off > 0; off >>= 1) {
            int other = __shfl_xor(key, off);
            key = other < key ? other : key;
        }
        if (lane == 0) {
            win_t[pos] = (unsigned char)(key >> 8);
            win_ch[pos] = (unsigned char)(key & 255);
        }
    }
    gg.sync();

    // ---------------- Phase D: conv2 + fire + inhibition + scatter ----------
    for (int p = wid; p < NPOS; p += nwaves) {
        int y2 = p / H2, x2 = p % H2;
        int tj[4]; int ccv[4];
#pragma unroll
        for (int k = 0; k < 4; k++) {
            int dy = k >> 1, dx = k & 1;
            int pi = (y2 + dy) * HP + (x2 + dx);
            tj[k] = win_t[pi];
            ccv[k] = win_ch[pi];
        }
        float wq[4][4];
        unsigned int mq[4];
        unsigned int lane_or = 0u;
#pragma unroll
        for (int q = 0; q < 4; q++) {
            int ch = q * 64 + lane;
#pragma unroll
            for (int k = 0; k < 4; k++)
                wq[q][k] = (tj[k] < 15) ? w2T[(k * C1_ + ccv[k]) * 256 + ch] : 0.0f;
            unsigned int m = 0u;
#pragma unroll
            for (int t = 0; t < T_; t++) {
                float v = 0.f;
#pragma unroll
                for (int k = 0; k < 4; k++) v += (t >= tj[k]) ? wq[q][k] : 0.f;
                m |= (v >= THR2) ? (1u << t) : 0u;
            }
            mq[q] = m;
            lane_or |= m;
        }
#pragma unroll
        for (int off = 32; off > 0; off >>= 1) lane_or |= __shfl_xor(lane_or, off);
        unsigned int om = lane_or;
        int count = __popc(om & 0x7FFFu);
        int earliest = 15 - count;
        earliest = earliest < 0 ? 0 : (earliest > 14 ? 14 : earliest);
        int alive = (om >> 14) & 1;

        unsigned long long best = 0ull;
        float bw0 = 0.f, bw1 = 0.f, bw2 = 0.f, bw3 = 0.f;
        unsigned int bm = 0u;
#pragma unroll
        for (int q = 0; q < 4; q++) {
            int ch = q * 64 + lane;
            float v = 0.f;
#pragma unroll
            for (int k = 0; k < 4; k++) v += (earliest >= tj[k]) ? wq[q][k] : 0.f;
            float zval = (v < THR2) ? 0.f : v;
            unsigned long long key =
                ((unsigned long long)__float_as_uint(zval) << 16) |
                (unsigned long long)(1023 - ch);
            if (key > best) {
                best = key;
                bw0 = wq[q][0]; bw1 = wq[q][1]; bw2 = wq[q][2]; bw3 = wq[q][3];
                bm = mq[q];
            }
        }
        unsigned long long gbest = best;
#pragma unroll
        for (int off = 32; off > 0; off >>= 1) {
            unsigned long long other = __shfl_xor(gbest, off);
            gbest = other > gbest ? other : gbest;
        }

        if (alive) {
            int wo = 1023 - (int)(gbest & 0xFFFFull);
            if ((wo & 63) == lane && best == gbest) {
                int nsp = __popc(bm & 0x7FFFu);
                int e2 = 15 - nsp;
                e2 = e2 < 0 ? 0 : (e2 > 14 ? 14 : e2);
                float vv = 0.f;
#pragma unroll
                for (int k = 0; k < 4; k++) {
                    float wk = (k == 0) ? bw0 : (k == 1) ? bw1 : (k == 2) ? bw2 : bw3;
                    vv += (e2 >= tj[k]) ? wk : 0.f;
                }
                vv = (vv < THR2) ? 0.f : vv;
                vals[p] = vv; nsp_arr[p] = nsp; ow_arr[p] = wo;
                if (nsp > 0) atomicMax(bigbits, __float_as_uint(vv));
#pragma unroll
                for (int t = 0; t < T_; t++) {
                    if ((bm >> t) & 1u) {
                        float vt = 0.f;
                        vt += (t >= tj[0]) ? bw0 : 0.f;
                        vt += (t >= tj[1]) ? bw1 : 0.f;
                        vt += (t >= tj[2]) ? bw2 : 0.f;
                        vt += (t >= tj[3]) ? bw3 : 0.f;
                        int idx = ((t * C2_ + wo) * H2 + y2) * H2 + x2;
                        v_out[idx] = vt;
                        s_out[idx] = 1.0f;
                    }
                }
            }
        } else if (lane == 0) {
            vals[p] = 0.f; nsp_arr[p] = 0; ow_arr[p] = 0;
        }
    }
}

// ===========================================================================
// Fallback path: round-7 kernels (validated), used if coop launch unavailable.
__global__ __launch_bounds__(256) void k_mega(const float* __restrict__ inp,
                                              const float* __restrict__ w1,
                                              const float* __restrict__ w2,
                                              unsigned int* __restrict__ maskg,
                                              float* __restrict__ w1T,
                                              float* __restrict__ w2T,
                                              unsigned int* __restrict__ bigbits,
                                              uint4* __restrict__ fill_dst,
                                              size_t nA, int nf) {
    __shared__ unsigned char tft[CIN * 20 * 20];
    __shared__ int cnt[16 * 256];
    int b = blockIdx.x;
    int tid = threadIdx.x;

    if (b < 100) {
        int ty0 = (b / 10) * 16, tx0 = (b % 10) * 16;
        for (int i = tid; i < CIN * 400; i += 256) {
            int ci = i / 400, rem = i % 400;
            int ly = rem / 20, lx = rem % 20;
            int y = ty0 + ly - 2, x = tx0 + lx - 2;
            unsigned char tv = 15;
            if ((unsigned)y < (unsigned)H0 && (unsigned)x < (unsigned)W0) {
                float c = 0.f;
                int base = ci * NPIX + y * W0 + x;
#pragma unroll
                for (int t = 0; t < T_; t++) c += inp[(size_t)t * NIN + base];
                tv = (unsigned char)(15 - (int)(c + 0.5f));
            }
            tft[i] = tv;
        }
        __syncthreads();

        int tyl = tid >> 4, txl = tid & 15;
        int pix = (ty0 + tyl) * W0 + (tx0 + txl);
        int* col = cnt + tid;
#pragma unroll
        for (int w = 0; w < 5; w++) {
            int j0 = w * 32, j1 = (w == 4) ? 150 : (j0 + 32);
#pragma unroll
            for (int q = 0; q < 16; q++) col[q * 256] = 0;
#pragma unroll 32
            for (int j = j0; j < j1; j++) {
                int ci = j / 25, r = j % 25, ky = r / 5, kx = r % 5;
                int tfv = tft[ci * 400 + (tyl + ky) * 20 + (txl + kx)];
                col[tfv * 256] |= 1u << (j & 31);
            }
#pragma unroll
            for (int t = 0; t < 15; t++)
                maskg[(size_t)(t * 5 + w) * NPIX + pix] = (unsigned)col[t * 256];
        }
    } else if (b < 175) {
        if (b == 100 && tid == 0) *bigbits = 0u;
        int idx = (b - 100) * 256 + tid;
        int j = idx >> 7, c = idx & 127;
        w1T[idx] = w1[c * 150 + j];
    } else if (b < 687) {
        int idx = (b - 175) * 256 + tid;
        int o = idx & 255, kcc = idx >> 8;
        int cc = kcc & 127, k = kcc >> 7;
        w2T[idx] = w2[o * 512 + cc * 4 + k];
    } else {
        size_t stride = (size_t)nf * 256;
        uint4 z = make_uint4(0u, 0u, 0u, 0u);
        for (size_t i = (size_t)(b - 687) * 256 + tid; i < nA; i += stride)
            fill_dst[i] = z;
    }
}

__global__ __launch_bounds__(256) void k1_main(const unsigned int* __restrict__ maskg,
                                               const float* __restrict__ w1T,
                                               unsigned char* __restrict__ fst1,
                                               uint4* __restrict__ fill_dst,
                                               size_t nA, size_t n16, int nf) {
    int b = blockIdx.x;
    int tid = threadIdx.x;
    if (b >= 6400) {
        size_t stride = (size_t)nf * 256;
        uint4 z = make_uint4(0u, 0u, 0u, 0u);
        for (size_t i = nA + (size_t)(b - 6400) * 256 + tid; i < n16; i += stride)
            fill_dst[i] = z;
        return;
    }
    int pix = b * 4 + (tid >> 6);
    int lane = tid & 63;
    const float* wb = w1T + 2 * lane;

    float v0 = 0.f, v1 = 0.f;
    int f0 = 15, f1 = 15;
    for (int t = 0; t < 15; ++t) {
        float b0 = 0.f, b1 = 0.f;
#pragma unroll
        for (int w = 0; w < 5; ++w) {
            unsigned int m = maskg[(size_t)(t * 5 + w) * NPIX + pix];
            int base = w * 32;
            while (m) {
                int j = base + __builtin_ctz(m);
                m &= m - 1;
                float2 ww = *(const float2*)(wb + j * C1_);
                b0 += ww.x; b1 += ww.y;
            }
        }
        v0 += b0; v1 += b1;
        f0 = (f0 == 15 && v0 >= THR1) ? t : f0;
        f1 = (f1 == 15 && v1 >= THR1) ? t : f1;
        if (__all((f0 < 15) & (f1 < 15))) break;
    }
    *(uchar2*)(fst1 + (size_t)pix * C1_ + 2 * lane) =
        make_uchar2((unsigned char)f0, (unsigned char)f1);
}

__global__ __launch_bounds__(256) void k2_pool(const unsigned char* __restrict__ fst1,
                                               unsigned char* __restrict__ win_t,
                                               unsigned char* __restrict__ win_ch) {
    int pos = blockIdx.x * 4 + (threadIdx.x >> 6);
    int lane = threadIdx.x & 63;
    if (pos >= HP * HP) return;
    int py = pos / HP, px = pos % HP;
    if (py == 0 || py == HP - 1 || px == 0 || px == HP - 1) {
        if (lane == 0) { win_t[pos] = 15; win_ch[pos] = 0; }
        return;
    }
    int y0 = 2 * py - 3, x0 = 2 * px - 3;
    int m0 = 15, m1 = 15;
#pragma unroll
    for (int dy = 0; dy < 2; dy++) {
        int y = y0 + dy;
        if ((unsigned)y < (unsigned)H0) {
#pragma unroll
            for (int dx = 0; dx < 2; dx++) {
                int x = x0 + dx;
                if ((unsigned)x < (unsigned)W0) {
                    uchar2 f = *(const uchar2*)(fst1 + (size_t)(y * W0 + x) * C1_ + 2 * lane);
                    m0 = f.x < m0 ? f.x : m0;
                    m1 = f.y < m1 ? f.y : m1;
                }
            }
        }
    }
    int k0 = (m0 << 8) | (2 * lane);
    int k1 = (m1 << 8) | (2 * lane + 1);
    int key = k0 < k1 ? k0 : k1;
#pragma unroll
    for (int off = 32; off > 0; off >>= 1) {
        int other = __shfl_xor(key, off);
        key = other < key ? other : key;
    }
    if (lane == 0) {
        win_t[pos] = (unsigned char)(key >> 8);
        win_ch[pos] = (unsigned char)(key & 255);
    }
}

__global__ __launch_bounds__(256) void kz_fill(uint4* __restrict__ dst, size_t n16,
                                               unsigned int* __restrict__ bigbits) {
    size_t stride = (size_t)gridDim.x * 256;
    uint4 z = make_uint4(0u, 0u, 0u, 0u);
    for (size_t i = (size_t)blockIdx.x * 256 + threadIdx.x; i < n16; i += stride)
        dst[i] = z;
    if (blockIdx.x == 0 && threadIdx.x == 0) *bigbits = 0u;
}

__global__ __launch_bounds__(256) void k3_conv2(const unsigned char* __restrict__ win_t,
                                                const unsigned char* __restrict__ win_ch,
                                                const float* __restrict__ w2T,
                                                float* __restrict__ s_out,
                                                float* __restrict__ v_out,
                                                float* __restrict__ vals,
                                                int* __restrict__ nsp_arr,
                                                int* __restrict__ ow_arr,
                                                unsigned int* __restrict__ bigbits) {
    int p = blockIdx.x * 4 + (threadIdx.x >> 6);
    int lane = threadIdx.x & 63;
    int y2 = p / H2, x2 = p % H2;

    int tj[4]; int ccv[4];
#pragma unroll
    for (int k = 0; k < 4; k++) {
        int dy = k >> 1, dx = k & 1;
        int pi = (y2 + dy) * HP + (x2 + dx);
        tj[k] = win_t[pi];
        ccv[k] = win_ch[pi];
    }

    float wq[4][4];
    unsigned int mq[4];
    unsigned int lane_or = 0u;
#pragma unroll
    for (int q = 0; q < 4; q++) {
        int ch = q * 64 + lane;
#pragma unroll
        for (int k = 0; k < 4; k++)
            wq[q][k] = (tj[k] < 15) ? w2T[(k * C1_ + ccv[k]) * 256 + ch] : 0.0f;
        unsigned int m = 0u;
#pragma unroll
        for (int t = 0; t < T_; t++) {
            float v = 0.f;
#pragma unroll
            for (int k = 0; k < 4; k++) v += (t >= tj[k]) ? wq[q][k] : 0.f;
            m |= (v >= THR2) ? (1u << t) : 0u;
        }
        mq[q] = m;
        lane_or |= m;
    }

#pragma unroll
    for (int off = 32; off > 0; off >>= 1) lane_or |= __shfl_xor(lane_or, off);
    unsigned int om = lane_or;
    int count = __popc(om & 0x7FFFu);
    int earliest = 15 - count;
    earliest = earliest < 0 ? 0 : (earliest > 14 ? 14 : earliest);
    int alive = (om >> 14) & 1;

    unsigned long long best = 0ull;
    float bw0 = 0.f, bw1 = 0.f, bw2 = 0.f, bw3 = 0.f;
    unsigned int bm = 0u;
#pragma unroll
    for (int q = 0; q < 4; q++) {
        int ch = q * 64 + lane;
        float v = 0.f;
#pragma unroll
        for (int k = 0; k < 4; k++) v += (earliest >= tj[k]) ? wq[q][k] : 0.f;
        float zval = (v < THR2) ? 0.f : v;
        unsigned long long key =
            ((unsigned long long)__float_as_uint(zval) << 16) |
            (unsigned long long)(1023 - ch);
        if (key > best) {
            best = key;
            bw0 = wq[q][0]; bw1 = wq[q][1]; bw2 = wq[q][2]; bw3 = wq[q][3];
            bm = mq[q];
        }
    }
    unsigned long long gbest = best;
#pragma unroll
    for (int off = 32; off > 0; off >>= 1) {
        unsigned long long other = __shfl_xor(gbest, off);
        gbest = other > gbest ? other : gbest;
    }

    if (alive) {
        int wo = 1023 - (int)(gbest & 0xFFFFull);
        if ((wo & 63) == lane && best == gbest) {
            int nsp = __popc(bm & 0x7FFFu);
            int e2 = 15 - nsp;
            e2 = e2 < 0 ? 0 : (e2 > 14 ? 14 : e2);
            float vv = 0.f;
#pragma unroll
            for (int k = 0; k < 4; k++) {
                float wk = (k == 0) ? bw0 : (k == 1) ? bw1 : (k == 2) ? bw2 : bw3;
                vv += (e2 >= tj[k]) ? wk : 0.f;
            }
            vv = (vv < THR2) ? 0.f : vv;
            vals[p] = vv; nsp_arr[p] = nsp; ow_arr[p] = wo;
            if (nsp > 0) atomicMax(bigbits, __float_as_uint(vv));
#pragma unroll
            for (int t = 0; t < T_; t++) {
                if ((bm >> t) & 1u) {
                    float vt = 0.f;
                    vt += (t >= tj[0]) ? bw0 : 0.f;
                    vt += (t >= tj[1]) ? bw1 : 0.f;
                    vt += (t >= tj[2]) ? bw2 : 0.f;
                    vt += (t >= tj[3]) ? bw3 : 0.f;
                    int idx = ((t * C2_ + wo) * H2 + y2) * H2 + x2;
                    v_out[idx] = vt;
                    s_out[idx] = 1.0f;
                }
            }
        }
    } else if (lane == 0) {
        vals[p] = 0.f; nsp_arr[p] = 0; ow_arr[p] = 0;
    }
}

// ---------------------------------------------------------------------------
// K4: greedy k-WTA (8 winners), 1024-thread block (validated).
__global__ __launch_bounds__(1024) void k4_kwta(const float* __restrict__ vals,
                                                const int* __restrict__ nsp,
                                                const int* __restrict__ ow,
                                                const unsigned int* __restrict__ bigbits,
                                                float* __restrict__ wout) {
    __shared__ float tot[NPOS];
    __shared__ short och[NPOS];
    __shared__ unsigned long long amax;
    int tid = threadIdx.x;
    float big = __uint_as_float(*bigbits) * 15.0f;

    for (int p = tid; p < NPOS; p += 1024) {
        int n = nsp[p];
        tot[p] = (n > 0) ? (float)n * (vals[p] + big) : 0.0f;
        och[p] = (short)ow[p];
    }
    if (tid == 0) amax = 0ull;
    __syncthreads();

    for (int it = 0; it < 8; it++) {
        unsigned long long best = 0ull;
        for (int p = tid; p < NPOS; p += 1024) {
            float tv = tot[p];
            if (tv > 0.0f) {
                unsigned int k = (unsigned)och[p] * (unsigned)NPOS + (unsigned)p;
                unsigned long long pk =
                    ((unsigned long long)__float_as_uint(tv) << 21) |
                    (unsigned long long)(0x1FFFFFu - k);
                best = pk > best ? pk : best;
            }
        }
#pragma unroll
        for (int off = 32; off > 0; off >>= 1) {
            unsigned long long other = __shfl_xor(best, off);
            best = other > best ? other : best;
        }
        if ((tid & 63) == 0) atomicMax(&amax, best);
        __syncthreads();
        unsigned long long mx = amax;
        __syncthreads();
        if (tid == 0) amax = 0ull;

        if (mx == 0ull) {
            if (tid == 0) {
                wout[it * 3 + 0] = -1.f; wout[it * 3 + 1] = -1.f; wout[it * 3 + 2] = -1.f;
            }
        } else {
            unsigned int k = 0x1FFFFFu - (unsigned)(mx & 0x1FFFFFull);
            int f = (int)(k / NPOS), pp = (int)(k % NPOS);
            int r = pp / H2, col = pp % H2;
            if (tid == 0) {
                wout[it * 3 + 0] = (float)f; wout[it * 3 + 1] = (float)r; wout[it * 3 + 2] = (float)col;
            }
            for (int p = tid; p < NPOS; p += 1024) {
                int pr = p / H2, pc = p % H2;
                bool kill = (och[p] == (short)f) ||
                            (pr >= r - 1 && pr <= r + 1 && pc >= col - 1 && pc <= col + 1);
                if (kill) tot[p] = 0.0f;
            }
        }
        __syncthreads();
    }
}

// ---------------------------------------------------------------------------
extern "C" void kernel_launch(void* const* d_in, const int* in_sizes, int n_in,
                              void* d_out, int out_size, void* d_ws, size_t ws_size,
                              hipStream_t stream) {
    const float* inp = (const float*)d_in[0];
    const float* w1  = (const float*)d_in[1];
    const float* w2  = (const float*)d_in[2];

    float* out = (float*)d_out;
    float* s_out = out;                    // [15,256,82,82]
    float* v_out = out + (size_t)NS;       // [15,256,82,82]
    float* wnr   = out + 2 * (size_t)NS;   // [8,3] as floats

    size_t need = (size_t)15 << 20;
    bool big_ws = ws_size >= need;
    char* scratch = big_ws ? (char*)d_ws
                           : (char*)d_out + (size_t)NS * sizeof(float);
    unsigned int* maskg = (unsigned int*)scratch;                   // 7.68 MB
    unsigned char* fst1 = (unsigned char*)(scratch + (8 << 20));    // 3.27 MB
    float* w1T = (float*)(scratch + (12 << 20));                    // 76.8 KB
    float* w2T = (float*)(scratch + (13 << 20));                    // 512 KB
    char* smol = big_ws ? (char*)d_ws + (14 << 20) : (char*)d_ws;
    unsigned char* win_t  = (unsigned char*)smol;
    unsigned char* win_ch = (unsigned char*)smol + 8192;
    float* vals = (float*)(smol + 16384);
    int*   nsp  = (int*)(smol + 49152);
    int*   ow   = (int*)(smol + 81920);
    unsigned int* bigbits = (unsigned int*)(smol + 114688);

    size_t n16 = (size_t)out_size / 4;     // out_size divisible by 4
    uint4* fill_dst = (uint4*)d_out;

    bool coop_done = false;
    if (big_ws) {
        int maxb = 0;
        hipError_t qe = hipOccupancyMaxActiveBlocksPerMultiprocessor(&maxb, k_coop, 256, 0);
        if (qe == hipSuccess && maxb >= 1) {
            int grid = maxb * 256;         // 256 CUs on MI355X
            if (grid > 1024) grid = 1024;
            void* args[] = {(void*)&inp, (void*)&w1, (void*)&w2, (void*)&maskg,
                            (void*)&w1T, (void*)&w2T, (void*)&fst1, (void*)&win_t,
                            (void*)&win_ch, (void*)&vals, (void*)&nsp, (void*)&ow,
                            (void*)&bigbits, (void*)&s_out, (void*)&v_out,
                            (void*)&fill_dst, (void*)&n16};
            hipError_t le = hipLaunchCooperativeKernel(k_coop, dim3(grid), dim3(256),
                                                       args, 0, stream);
            coop_done = (le == hipSuccess);
        }
    }

    if (!coop_done) {
        size_t nA  = big_ws ? n16 / 2 : 0;
        int nf1 = big_ws ? NF1 : 0;
        int nf2 = big_ws ? NF2 : 0;
        hipLaunchKernelGGL(k_mega, dim3(687 + nf1), dim3(256), 0, stream,
                           inp, w1, w2, maskg, w1T, w2T, bigbits, fill_dst, nA, nf1);
        hipLaunchKernelGGL(k1_main, dim3(6400 + nf2), dim3(256), 0, stream,
                           maskg, w1T, fst1, fill_dst, nA, n16, nf2);
        hipLaunchKernelGGL(k2_pool, dim3((HP * HP + 3) / 4), dim3(256), 0, stream,
                           fst1, win_t, win_ch);
        if (!big_ws)
            hipLaunchKernelGGL(kz_fill, dim3(4096), dim3(256), 0, stream,
                               fill_dst, n16, bigbits);
        hipLaunchKernelGGL(k3_conv2, dim3(NPOS / 4), dim3(256), 0, stream,
                           win_t, win_ch, w2T, s_out, v_out, vals, nsp, ow, bigbits);
    }
    hipLaunchKernelGGL(k4_kwta, dim3(1), dim3(1024), 0, stream, vals, nsp, ow, bigbits, wnr);
}

// Round 9
// 199.714 us; speedup vs baseline: 2.3806x; 2.3806x over previous
//
#include <hip/hip_runtime.h>

#define T_ 15
#define CIN 6
#define H0 160
#define W0 160
#define C1_ 128
#define C2_ 256
#define HP 83            // padded pooled grid (83x83)
#define H2 82            // conv2 output (82x82)
#define NPIX (H0*W0)     // 25600
#define NIN (CIN*NPIX)   // 153600
#define NPOS (H2*H2)     // 6724
#define NS (T_*C2_*NPOS) // 25,820,160 elements per s/v output
#define THR1 10.0f
#define THR2 1.0f
#define NF1 1024         // fill blocks in k_mega (first quarter of d_out)
#define NF2 3072         // fill blocks in k1 (remaining three quarters)

// ---------------------------------------------------------------------------
// MEGA prep kernel.
//   b in [0,100):        per-tile tap sort -> time-bitmasks maskg[t][w][pix]
//   b in [100,175):      w1T[j][c] transpose (+ b==100 zeroes bigbits)
//   b in [175,687):      w2T[k][cc][o] transpose
//   b in [687,687+nf):   zero-fill first `nA` uint4s of d_out
// Fill split rationale (r8): k_mega's compute (~8us of sort) hides ~50MB of
// fill; k1's conv1 (~20us latency-bound) hides the rest. 50/50 made k_mega
// fill-dominated (17us); 25/75 balances both.
__global__ __launch_bounds__(256) void k_mega(const float* __restrict__ inp,
                                              const float* __restrict__ w1,
                                              const float* __restrict__ w2,
                                              unsigned int* __restrict__ maskg,
                                              float* __restrict__ w1T,
                                              float* __restrict__ w2T,
                                              unsigned int* __restrict__ bigbits,
                                              uint4* __restrict__ fill_dst,
                                              size_t nA, int nf) {
    __shared__ unsigned char tft[CIN * 20 * 20]; // 2400 B tf tile (with halo)
    __shared__ int cnt[16 * 256];                // per-lane bitmask columns
    int b = blockIdx.x;
    int tid = threadIdx.x;

    if (b < 100) {
        // ---- tap sort tile ----
        int ty0 = (b / 10) * 16, tx0 = (b % 10) * 16;
        for (int i = tid; i < CIN * 400; i += 256) {
            int ci = i / 400, rem = i % 400;
            int ly = rem / 20, lx = rem % 20;
            int y = ty0 + ly - 2, x = tx0 + lx - 2;
            unsigned char tv = 15;
            if ((unsigned)y < (unsigned)H0 && (unsigned)x < (unsigned)W0) {
                float c = 0.f;
                int base = ci * NPIX + y * W0 + x;
#pragma unroll
                for (int t = 0; t < T_; t++) c += inp[(size_t)t * NIN + base];
                tv = (unsigned char)(15 - (int)(c + 0.5f));
            }
            tft[i] = tv;
        }
        __syncthreads();

        int tyl = tid >> 4, txl = tid & 15;
        int pix = (ty0 + tyl) * W0 + (tx0 + txl);
        int* col = cnt + tid;   // private column: bank = tid%32, conflict-free

#pragma unroll
        for (int w = 0; w < 5; w++) {
            int j0 = w * 32, j1 = (w == 4) ? 150 : (j0 + 32);
#pragma unroll
            for (int q = 0; q < 16; q++) col[q * 256] = 0;
#pragma unroll 32
            for (int j = j0; j < j1; j++) {
                int ci = j / 25, r = j % 25, ky = r / 5, kx = r % 5;
                int tfv = tft[ci * 400 + (tyl + ky) * 20 + (txl + kx)];
                col[tfv * 256] |= 1u << (j & 31);   // slot 15 = trash
            }
#pragma unroll
            for (int t = 0; t < 15; t++)
                maskg[(size_t)(t * 5 + w) * NPIX + pix] = (unsigned)col[t * 256];
        }
    } else if (b < 175) {
        // ---- w1T[j][c] = w1[c][j] ----
        if (b == 100 && tid == 0) *bigbits = 0u;
        int idx = (b - 100) * 256 + tid;      // < 19200
        int j = idx >> 7, c = idx & 127;
        w1T[idx] = w1[c * 150 + j];
    } else if (b < 687) {
        // ---- w2T[k][cc][o] = w2[o][cc][k] ----
        int idx = (b - 175) * 256 + tid;      // < 131072
        int o = idx & 255, kcc = idx >> 8;
        int cc = kcc & 127, k = kcc >> 7;
        w2T[idx] = w2[o * 512 + cc * 4 + k];
    } else {
        // ---- zero-fill first quarter of d_out ----
        size_t stride = (size_t)nf * 256;
        uint4 z = make_uint4(0u, 0u, 0u, 0u);
        for (size_t i = (size_t)(b - 687) * 256 + tid; i < nA; i += stride)
            fill_dst[i] = z;
    }
}

// ---------------------------------------------------------------------------
// K1: wave = ONE pixel, lane = channel pair (2c,2c+1). Taps consumed
// bucket-by-bucket via time-bitmasks (ctz = j-ascending within bucket ->
// exact same fp32 summation tree as the validated kernel). Early-exit when
// all 128 channels crossed. Blocks [6400, 6400+nf) zero-fill the rest of
// d_out (hides under the latency-bound compute).
__global__ __launch_bounds__(256) void k1_main(const unsigned int* __restrict__ maskg,
                                               const float* __restrict__ w1T,
                                               unsigned char* __restrict__ fst1,
                                               uint4* __restrict__ fill_dst,
                                               size_t nA, size_t n16, int nf) {
    int b = blockIdx.x;
    int tid = threadIdx.x;
    if (b >= 6400) {
        size_t stride = (size_t)nf * 256;
        uint4 z = make_uint4(0u, 0u, 0u, 0u);
        for (size_t i = nA + (size_t)(b - 6400) * 256 + tid; i < n16; i += stride)
            fill_dst[i] = z;
        return;
    }
    int pix = b * 4 + (tid >> 6);
    int lane = tid & 63;
    const float* wb = w1T + 2 * lane;

    float v0 = 0.f, v1 = 0.f;
    int f0 = 15, f1 = 15;
    for (int t = 0; t < 15; ++t) {
        float b0 = 0.f, b1 = 0.f;
#pragma unroll
        for (int w = 0; w < 5; ++w) {
            unsigned int m = maskg[(size_t)(t * 5 + w) * NPIX + pix]; // wave-uniform
            int base = w * 32;
            while (m) {
                int j = base + __builtin_ctz(m);
                m &= m - 1;
                float2 ww = *(const float2*)(wb + j * C1_); // coalesced 512B
                b0 += ww.x; b1 += ww.y;
            }
        }
        v0 += b0; v1 += b1;
        f0 = (f0 == 15 && v0 >= THR1) ? t : f0;
        f1 = (f1 == 15 && v1 >= THR1) ? t : f1;
        if (__all((f0 < 15) & (f1 < 15))) break;
    }
    *(uchar2*)(fst1 + (size_t)pix * C1_ + 2 * lane) =
        make_uchar2((unsigned char)f0, (unsigned char)f1);
}

// ---------------------------------------------------------------------------
// K2: wave = one padded-grid position, lane = channel pair. pool-min over the
// 2x2 window of fst1[pix][ch], then winner = min (tf<<8 | ch) across channels.
__global__ __launch_bounds__(256) void k2_pool(const unsigned char* __restrict__ fst1,
                                               unsigned char* __restrict__ win_t,
                                               unsigned char* __restrict__ win_ch) {
    int pos = blockIdx.x * 4 + (threadIdx.x >> 6);
    int lane = threadIdx.x & 63;
    if (pos >= HP * HP) return;
    int py = pos / HP, px = pos % HP;
    if (py == 0 || py == HP - 1 || px == 0 || px == HP - 1) {
        if (lane == 0) { win_t[pos] = 15; win_ch[pos] = 0; }
        return;
    }
    int y0 = 2 * py - 3, x0 = 2 * px - 3;
    int m0 = 15, m1 = 15;
#pragma unroll
    for (int dy = 0; dy < 2; dy++) {
        int y = y0 + dy;
        if ((unsigned)y < (unsigned)H0) {
#pragma unroll
            for (int dx = 0; dx < 2; dx++) {
                int x = x0 + dx;
                if ((unsigned)x < (unsigned)W0) {
                    uchar2 f = *(const uchar2*)(fst1 + (size_t)(y * W0 + x) * C1_ + 2 * lane);
                    m0 = f.x < m0 ? f.x : m0;
                    m1 = f.y < m1 ? f.y : m1;
                }
            }
        }
    }
    int k0 = (m0 << 8) | (2 * lane);
    int k1 = (m1 << 8) | (2 * lane + 1);
    int key = k0 < k1 ? k0 : k1;
#pragma unroll
    for (int off = 32; off > 0; off >>= 1) {
        int other = __shfl_xor(key, off);
        key = other < key ? other : key;
    }
    if (lane == 0) {
        win_t[pos] = (unsigned char)(key >> 8);
        win_ch[pos] = (unsigned char)(key & 255);
    }
}

// ---------------------------------------------------------------------------
// KZ: fallback full zero-fill (only if ws_size is unexpectedly small).
__global__ __launch_bounds__(256) void kz_fill(uint4* __restrict__ dst, size_t n16,
                                               unsigned int* __restrict__ bigbits) {
    size_t stride = (size_t)gridDim.x * 256;
    uint4 z = make_uint4(0u, 0u, 0u, 0u);
    for (size_t i = (size_t)blockIdx.x * 256 + threadIdx.x; i < n16; i += stride)
        dst[i] = z;
    if (blockIdx.x == 0 && threadIdx.x == 0) *bigbits = 0u;
}

// ---------------------------------------------------------------------------
// K3: wave = one output position, lane = 4 channels (q*64+lane). No LDS, no
// barriers; register state + shfl butterflies. Arithmetic bit-identical to
// the validated block version.
__global__ __launch_bounds__(256) void k3_conv2(const unsigned char* __restrict__ win_t,
                                                const unsigned char* __restrict__ win_ch,
                                                const float* __restrict__ w2T,
                                                float* __restrict__ s_out,
                                                float* __restrict__ v_out,
                                                float* __restrict__ vals,
                                                int* __restrict__ nsp_arr,
                                                int* __restrict__ ow_arr,
                                                unsigned int* __restrict__ bigbits) {
    int p = blockIdx.x * 4 + (threadIdx.x >> 6);   // grid exact: 1681*4 = NPOS
    int lane = threadIdx.x & 63;
    int y2 = p / H2, x2 = p % H2;

    int tj[4]; int ccv[4];
#pragma unroll
    for (int k = 0; k < 4; k++) {
        int dy = k >> 1, dx = k & 1;
        int pi = (y2 + dy) * HP + (x2 + dx);
        tj[k] = win_t[pi];          // wave-uniform loads (broadcast)
        ccv[k] = win_ch[pi];
    }

    float wq[4][4];
    unsigned int mq[4];
    unsigned int lane_or = 0u;
#pragma unroll
    for (int q = 0; q < 4; q++) {
        int ch = q * 64 + lane;
#pragma unroll
        for (int k = 0; k < 4; k++)
            wq[q][k] = (tj[k] < 15) ? w2T[(k * C1_ + ccv[k]) * 256 + ch] : 0.0f;
        unsigned int m = 0u;
#pragma unroll
        for (int t = 0; t < T_; t++) {
            float v = 0.f;
#pragma unroll
            for (int k = 0; k < 4; k++) v += (t >= tj[k]) ? wq[q][k] : 0.f;
            m |= (v >= THR2) ? (1u << t) : 0u;   // zz>0 <=> v>=1
        }
        mq[q] = m;
        lane_or |= m;
    }

#pragma unroll
    for (int off = 32; off > 0; off >>= 1) lane_or |= __shfl_xor(lane_or, off);
    unsigned int om = lane_or;
    int count = __popc(om & 0x7FFFu);
    int earliest = 15 - count;
    earliest = earliest < 0 ? 0 : (earliest > 14 ? 14 : earliest);
    int alive = (om >> 14) & 1;

    unsigned long long best = 0ull;
    float bw0 = 0.f, bw1 = 0.f, bw2 = 0.f, bw3 = 0.f;
    unsigned int bm = 0u;
#pragma unroll
    for (int q = 0; q < 4; q++) {
        int ch = q * 64 + lane;
        float v = 0.f;
#pragma unroll
        for (int k = 0; k < 4; k++) v += (earliest >= tj[k]) ? wq[q][k] : 0.f;
        float zval = (v < THR2) ? 0.f : v;
        unsigned long long key =
            ((unsigned long long)__float_as_uint(zval) << 16) |
            (unsigned long long)(1023 - ch);
        if (key > best) {
            best = key;
            bw0 = wq[q][0]; bw1 = wq[q][1]; bw2 = wq[q][2]; bw3 = wq[q][3];
            bm = mq[q];
        }
    }
    unsigned long long gbest = best;
#pragma unroll
    for (int off = 32; off > 0; off >>= 1) {
        unsigned long long other = __shfl_xor(gbest, off);
        gbest = other > gbest ? other : gbest;
    }

    if (alive) {
        int wo = 1023 - (int)(gbest & 0xFFFFull);
        if ((wo & 63) == lane && best == gbest) {
            int nsp = __popc(bm & 0x7FFFu);
            int e2 = 15 - nsp;
            e2 = e2 < 0 ? 0 : (e2 > 14 ? 14 : e2);
            float vv = 0.f;
#pragma unroll
            for (int k = 0; k < 4; k++) {
                float wk = (k == 0) ? bw0 : (k == 1) ? bw1 : (k == 2) ? bw2 : bw3;
                vv += (e2 >= tj[k]) ? wk : 0.f;
            }
            vv = (vv < THR2) ? 0.f : vv;
            vals[p] = vv; nsp_arr[p] = nsp; ow_arr[p] = wo;
            if (nsp > 0) atomicMax(bigbits, __float_as_uint(vv));
#pragma unroll
            for (int t = 0; t < T_; t++) {
                if ((bm >> t) & 1u) {
                    float vt = 0.f;
                    vt += (t >= tj[0]) ? bw0 : 0.f;
                    vt += (t >= tj[1]) ? bw1 : 0.f;
                    vt += (t >= tj[2]) ? bw2 : 0.f;
                    vt += (t >= tj[3]) ? bw3 : 0.f;
                    int idx = ((t * C2_ + wo) * H2 + y2) * H2 + x2;
                    v_out[idx] = vt;
                    s_out[idx] = 1.0f;
                }
            }
        }
    } else if (lane == 0) {
        vals[p] = 0.f; nsp_arr[p] = 0; ow_arr[p] = 0;
    }
}

// ---------------------------------------------------------------------------
// K4: greedy k-WTA (8 winners), 1024-thread block (validated; TLP hides LDS
// latency — the 64-thread variant was 80x slower). Exact reference tie-break.
__global__ __launch_bounds__(1024) void k4_kwta(const float* __restrict__ vals,
                                                const int* __restrict__ nsp,
                                                const int* __restrict__ ow,
                                                const unsigned int* __restrict__ bigbits,
                                                float* __restrict__ wout) {
    __shared__ float tot[NPOS];
    __shared__ short och[NPOS];
    __shared__ unsigned long long amax;
    int tid = threadIdx.x;
    float big = __uint_as_float(*bigbits) * 15.0f;

    for (int p = tid; p < NPOS; p += 1024) {
        int n = nsp[p];
        tot[p] = (n > 0) ? (float)n * (vals[p] + big) : 0.0f;
        och[p] = (short)ow[p];
    }
    if (tid == 0) amax = 0ull;
    __syncthreads();

    for (int it = 0; it < 8; it++) {
        unsigned long long best = 0ull;
        for (int p = tid; p < NPOS; p += 1024) {
            float tv = tot[p];
            if (tv > 0.0f) {
                unsigned int k = (unsigned)och[p] * (unsigned)NPOS + (unsigned)p;
                unsigned long long pk =
                    ((unsigned long long)__float_as_uint(tv) << 21) |
                    (unsigned long long)(0x1FFFFFu - k);
                best = pk > best ? pk : best;
            }
        }
#pragma unroll
        for (int off = 32; off > 0; off >>= 1) {
            unsigned long long other = __shfl_xor(best, off);
            best = other > best ? other : best;
        }
        if ((tid & 63) == 0) atomicMax(&amax, best);
        __syncthreads();
        unsigned long long mx = amax;
        __syncthreads();
        if (tid == 0) amax = 0ull;

        if (mx == 0ull) {
            if (tid == 0) {
                wout[it * 3 + 0] = -1.f; wout[it * 3 + 1] = -1.f; wout[it * 3 + 2] = -1.f;
            }
        } else {
            unsigned int k = 0x1FFFFFu - (unsigned)(mx & 0x1FFFFFull);
            int f = (int)(k / NPOS), pp = (int)(k % NPOS);
            int r = pp / H2, col = pp % H2;
            if (tid == 0) {
                wout[it * 3 + 0] = (float)f; wout[it * 3 + 1] = (float)r; wout[it * 3 + 2] = (float)col;
            }
            for (int p = tid; p < NPOS; p += 1024) {
                int pr = p / H2, pc = p % H2;
                bool kill = (och[p] == (short)f) ||
                            (pr >= r - 1 && pr <= r + 1 && pc >= col - 1 && pc <= col + 1);
                if (kill) tot[p] = 0.0f;
            }
        }
        __syncthreads();
    }
}

// ---------------------------------------------------------------------------
extern "C" void kernel_launch(void* const* d_in, const int* in_sizes, int n_in,
                              void* d_out, int out_size, void* d_ws, size_t ws_size,
                              hipStream_t stream) {
    const float* inp = (const float*)d_in[0];
    const float* w1  = (const float*)d_in[1];
    const float* w2  = (const float*)d_in[2];

    float* out = (float*)d_out;
    float* s_out = out;                    // [15,256,82,82]
    float* v_out = out + (size_t)NS;       // [15,256,82,82]
    float* wnr   = out + 2 * (size_t)NS;   // [8,3] as floats

    size_t need = (size_t)15 << 20;
    bool big_ws = ws_size >= need;
    char* scratch = big_ws ? (char*)d_ws
                           : (char*)d_out + (size_t)NS * sizeof(float);
    unsigned int* maskg = (unsigned int*)scratch;                   // 7.68 MB
    unsigned char* fst1 = (unsigned char*)(scratch + (8 << 20));    // 3.27 MB
    float* w1T = (float*)(scratch + (12 << 20));                    // 76.8 KB
    float* w2T = (float*)(scratch + (13 << 20));                    // 512 KB
    char* smol = big_ws ? (char*)d_ws + (14 << 20) : (char*)d_ws;
    unsigned char* win_t  = (unsigned char*)smol;
    unsigned char* win_ch = (unsigned char*)smol + 8192;
    float* vals = (float*)(smol + 16384);
    int*   nsp  = (int*)(smol + 49152);
    int*   ow   = (int*)(smol + 81920);
    unsigned int* bigbits = (unsigned int*)(smol + 114688);

    size_t n16 = (size_t)out_size / 4;     // out_size divisible by 4
    size_t nA  = big_ws ? n16 / 4 : 0;     // k_mega fills [0,nA), k1 fills [nA,n16)
    int nf1 = big_ws ? NF1 : 0;
    int nf2 = big_ws ? NF2 : 0;

    hipLaunchKernelGGL(k_mega, dim3(687 + nf1), dim3(256), 0, stream,
                       inp, w1, w2, maskg, w1T, w2T, bigbits, (uint4*)d_out, nA, nf1);
    hipLaunchKernelGGL(k1_main, dim3(6400 + nf2), dim3(256), 0, stream,
                       maskg, w1T, fst1, (uint4*)d_out, nA, n16, nf2);
    hipLaunchKernelGGL(k2_pool, dim3((HP * HP + 3) / 4), dim3(256), 0, stream,
                       fst1, win_t, win_ch);
    if (!big_ws)
        hipLaunchKernelGGL(kz_fill, dim3(4096), dim3(256), 0, stream,
                           (uint4*)d_out, n16, bigbits);
    hipLaunchKernelGGL(k3_conv2, dim3(NPOS / 4), dim3(256), 0, stream,
                       win_t, win_ch, w2T, s_out, v_out, vals, nsp, ow, bigbits);
    hipLaunchKernelGGL(k4_kwta, dim3(1), dim3(1024), 0, stream, vals, nsp, ow, bigbits, wnr);
}

// Round 10
// 199.267 us; speedup vs baseline: 2.3859x; 1.0022x over previous
//
#include <hip/hip_runtime.h>

#define T_ 15
#define CIN 6
#define H0 160
#define W0 160
#define C1_ 128
#define C2_ 256
#define HP 83            // padded pooled grid (83x83)
#define H2 82            // conv2 output (82x82)
#define NPIX (H0*W0)     // 25600
#define NIN (CIN*NPIX)   // 153600
#define NPOS (H2*H2)     // 6724
#define NS (T_*C2_*NPOS) // 25,820,160 elements per s/v output
#define THR1 10.0f
#define THR2 1.0f
#define NF1 1024         // fill blocks in k_mega (first quarter of d_out)
#define NF2 3072         // fill blocks in k1 (remaining three quarters)

// ---------------------------------------------------------------------------
// MEGA prep kernel.
//   b in [0,100):        per-tile tap sort -> time-bitmasks maskg[t][w][pix]
//   b in [100,175):      w1T[j][c] transpose (+ b==100 zeroes bigbits)
//   b in [175,687):      w2T[k][cc][o] transpose
//   b in [687,687+nf):   zero-fill first `nA` uint4s of d_out
// Fill split rationale (r8): k_mega's compute (~8us of sort) hides ~50MB of
// fill; k1's conv1 (~20us latency-bound) hides the rest. 50/50 made k_mega
// fill-dominated (17us); 25/75 balances both.
__global__ __launch_bounds__(256) void k_mega(const float* __restrict__ inp,
                                              const float* __restrict__ w1,
                                              const float* __restrict__ w2,
                                              unsigned int* __restrict__ maskg,
                                              float* __restrict__ w1T,
                                              float* __restrict__ w2T,
                                              unsigned int* __restrict__ bigbits,
                                              uint4* __restrict__ fill_dst,
                                              size_t nA, int nf) {
    __shared__ unsigned char tft[CIN * 20 * 20]; // 2400 B tf tile (with halo)
    __shared__ int cnt[16 * 256];                // per-lane bitmask columns
    int b = blockIdx.x;
    int tid = threadIdx.x;

    if (b < 100) {
        // ---- tap sort tile ----
        int ty0 = (b / 10) * 16, tx0 = (b % 10) * 16;
        for (int i = tid; i < CIN * 400; i += 256) {
            int ci = i / 400, rem = i % 400;
            int ly = rem / 20, lx = rem % 20;
            int y = ty0 + ly - 2, x = tx0 + lx - 2;
            unsigned char tv = 15;
            if ((unsigned)y < (unsigned)H0 && (unsigned)x < (unsigned)W0) {
                float c = 0.f;
                int base = ci * NPIX + y * W0 + x;
#pragma unroll
                for (int t = 0; t < T_; t++) c += inp[(size_t)t * NIN + base];
                tv = (unsigned char)(15 - (int)(c + 0.5f));
            }
            tft[i] = tv;
        }
        __syncthreads();

        int tyl = tid >> 4, txl = tid & 15;
        int pix = (ty0 + tyl) * W0 + (tx0 + txl);
        int* col = cnt + tid;   // private column: bank = tid%32, conflict-free

#pragma unroll
        for (int w = 0; w < 5; w++) {
            int j0 = w * 32, j1 = (w == 4) ? 150 : (j0 + 32);
#pragma unroll
            for (int q = 0; q < 16; q++) col[q * 256] = 0;
#pragma unroll 32
            for (int j = j0; j < j1; j++) {
                int ci = j / 25, r = j % 25, ky = r / 5, kx = r % 5;
                int tfv = tft[ci * 400 + (tyl + ky) * 20 + (txl + kx)];
                col[tfv * 256] |= 1u << (j & 31);   // slot 15 = trash
            }
#pragma unroll
            for (int t = 0; t < 15; t++)
                maskg[(size_t)(t * 5 + w) * NPIX + pix] = (unsigned)col[t * 256];
        }
    } else if (b < 175) {
        // ---- w1T[j][c] = w1[c][j] ----
        if (b == 100 && tid == 0) *bigbits = 0u;
        int idx = (b - 100) * 256 + tid;      // < 19200
        int j = idx >> 7, c = idx & 127;
        w1T[idx] = w1[c * 150 + j];
    } else if (b < 687) {
        // ---- w2T[k][cc][o] = w2[o][cc][k] ----
        int idx = (b - 175) * 256 + tid;      // < 131072
        int o = idx & 255, kcc = idx >> 8;
        int cc = kcc & 127, k = kcc >> 7;
        w2T[idx] = w2[o * 512 + cc * 4 + k];
    } else {
        // ---- zero-fill first quarter of d_out ----
        size_t stride = (size_t)nf * 256;
        uint4 z = make_uint4(0u, 0u, 0u, 0u);
        for (size_t i = (size_t)(b - 687) * 256 + tid; i < nA; i += stride)
            fill_dst[i] = z;
    }
}

// ---------------------------------------------------------------------------
// K1: wave = ONE pixel, lane = channel pair (2c,2c+1). Taps consumed
// bucket-by-bucket via time-bitmasks (ctz = j-ascending within bucket ->
// exact same fp32 summation tree as the validated kernel). Early-exit when
// all 128 channels crossed. Blocks [6400, 6400+nf) zero-fill the rest of
// d_out (hides under the latency-bound compute).
__global__ __launch_bounds__(256) void k1_main(const unsigned int* __restrict__ maskg,
                                               const float* __restrict__ w1T,
                                               unsigned char* __restrict__ fst1,
                                               uint4* __restrict__ fill_dst,
                                               size_t nA, size_t n16, int nf) {
    int b = blockIdx.x;
    int tid = threadIdx.x;
    if (b >= 6400) {
        size_t stride = (size_t)nf * 256;
        uint4 z = make_uint4(0u, 0u, 0u, 0u);
        for (size_t i = nA + (size_t)(b - 6400) * 256 + tid; i < n16; i += stride)
            fill_dst[i] = z;
        return;
    }
    int pix = b * 4 + (tid >> 6);
    int lane = tid & 63;
    const float* wb = w1T + 2 * lane;

    float v0 = 0.f, v1 = 0.f;
    int f0 = 15, f1 = 15;
    for (int t = 0; t < 15; ++t) {
        float b0 = 0.f, b1 = 0.f;
#pragma unroll
        for (int w = 0; w < 5; ++w) {
            unsigned int m = maskg[(size_t)(t * 5 + w) * NPIX + pix]; // wave-uniform
            int base = w * 32;
            while (m) {
                int j = base + __builtin_ctz(m);
                m &= m - 1;
                float2 ww = *(const float2*)(wb + j * C1_); // coalesced 512B
                b0 += ww.x; b1 += ww.y;
            }
        }
        v0 += b0; v1 += b1;
        f0 = (f0 == 15 && v0 >= THR1) ? t : f0;
        f1 = (f1 == 15 && v1 >= THR1) ? t : f1;
        if (__all((f0 < 15) & (f1 < 15))) break;
    }
    *(uchar2*)(fst1 + (size_t)pix * C1_ + 2 * lane) =
        make_uchar2((unsigned char)f0, (unsigned char)f1);
}

// ---------------------------------------------------------------------------
// K2: wave = one padded-grid position, lane = channel pair. pool-min over the
// 2x2 window of fst1[pix][ch], then winner = min (tf<<8 | ch) across channels.
__global__ __launch_bounds__(256) void k2_pool(const unsigned char* __restrict__ fst1,
                                               unsigned char* __restrict__ win_t,
                                               unsigned char* __restrict__ win_ch) {
    int pos = blockIdx.x * 4 + (threadIdx.x >> 6);
    int lane = threadIdx.x & 63;
    if (pos >= HP * HP) return;
    int py = pos / HP, px = pos % HP;
    if (py == 0 || py == HP - 1 || px == 0 || px == HP - 1) {
        if (lane == 0) { win_t[pos] = 15; win_ch[pos] = 0; }
        return;
    }
    int y0 = 2 * py - 3, x0 = 2 * px - 3;
    int m0 = 15, m1 = 15;
#pragma unroll
    for (int dy = 0; dy < 2; dy++) {
        int y = y0 + dy;
        if ((unsigned)y < (unsigned)H0) {
#pragma unroll
            for (int dx = 0; dx < 2; dx++) {
                int x = x0 + dx;
                if ((unsigned)x < (unsigned)W0) {
                    uchar2 f = *(const uchar2*)(fst1 + (size_t)(y * W0 + x) * C1_ + 2 * lane);
                    m0 = f.x < m0 ? f.x : m0;
                    m1 = f.y < m1 ? f.y : m1;
                }
            }
        }
    }
    int k0 = (m0 << 8) | (2 * lane);
    int k1 = (m1 << 8) | (2 * lane + 1);
    int key = k0 < k1 ? k0 : k1;
#pragma unroll
    for (int off = 32; off > 0; off >>= 1) {
        int other = __shfl_xor(key, off);
        key = other < key ? other : key;
    }
    if (lane == 0) {
        win_t[pos] = (unsigned char)(key >> 8);
        win_ch[pos] = (unsigned char)(key & 255);
    }
}

// ---------------------------------------------------------------------------
// KZ: fallback full zero-fill (only if ws_size is unexpectedly small).
__global__ __launch_bounds__(256) void kz_fill(uint4* __restrict__ dst, size_t n16,
                                               unsigned int* __restrict__ bigbits) {
    size_t stride = (size_t)gridDim.x * 256;
    uint4 z = make_uint4(0u, 0u, 0u, 0u);
    for (size_t i = (size_t)blockIdx.x * 256 + threadIdx.x; i < n16; i += stride)
        dst[i] = z;
    if (blockIdx.x == 0 && threadIdx.x == 0) *bigbits = 0u;
}

// ---------------------------------------------------------------------------
// K3: wave = one output position, lane = 4 channels (q*64+lane). No LDS, no
// barriers; register state + shfl butterflies. Arithmetic bit-identical to
// the validated block version.
__global__ __launch_bounds__(256) void k3_conv2(const unsigned char* __restrict__ win_t,
                                                const unsigned char* __restrict__ win_ch,
                                                const float* __restrict__ w2T,
                                                float* __restrict__ s_out,
                                                float* __restrict__ v_out,
                                                float* __restrict__ vals,
                                                int* __restrict__ nsp_arr,
                                                int* __restrict__ ow_arr,
                                                unsigned int* __restrict__ bigbits) {
    int p = blockIdx.x * 4 + (threadIdx.x >> 6);   // grid exact: 1681*4 = NPOS
    int lane = threadIdx.x & 63;
    int y2 = p / H2, x2 = p % H2;

    int tj[4]; int ccv[4];
#pragma unroll
    for (int k = 0; k < 4; k++) {
        int dy = k >> 1, dx = k & 1;
        int pi = (y2 + dy) * HP + (x2 + dx);
        tj[k] = win_t[pi];          // wave-uniform loads (broadcast)
        ccv[k] = win_ch[pi];
    }

    float wq[4][4];
    unsigned int mq[4];
    unsigned int lane_or = 0u;
#pragma unroll
    for (int q = 0; q < 4; q++) {
        int ch = q * 64 + lane;
#pragma unroll
        for (int k = 0; k < 4; k++)
            wq[q][k] = (tj[k] < 15) ? w2T[(k * C1_ + ccv[k]) * 256 + ch] : 0.0f;
        unsigned int m = 0u;
#pragma unroll
        for (int t = 0; t < T_; t++) {
            float v = 0.f;
#pragma unroll
            for (int k = 0; k < 4; k++) v += (t >= tj[k]) ? wq[q][k] : 0.f;
            m |= (v >= THR2) ? (1u << t) : 0u;   // zz>0 <=> v>=1
        }
        mq[q] = m;
        lane_or |= m;
    }

#pragma unroll
    for (int off = 32; off > 0; off >>= 1) lane_or |= __shfl_xor(lane_or, off);
    unsigned int om = lane_or;
    int count = __popc(om & 0x7FFFu);
    int earliest = 15 - count;
    earliest = earliest < 0 ? 0 : (earliest > 14 ? 14 : earliest);
    int alive = (om >> 14) & 1;

    unsigned long long best = 0ull;
    float bw0 = 0.f, bw1 = 0.f, bw2 = 0.f, bw3 = 0.f;
    unsigned int bm = 0u;
#pragma unroll
    for (int q = 0; q < 4; q++) {
        int ch = q * 64 + lane;
        float v = 0.f;
#pragma unroll
        for (int k = 0; k < 4; k++) v += (earliest >= tj[k]) ? wq[q][k] : 0.f;
        float zval = (v < THR2) ? 0.f : v;
        unsigned long long key =
            ((unsigned long long)__float_as_uint(zval) << 16) |
            (unsigned long long)(1023 - ch);
        if (key > best) {
            best = key;
            bw0 = wq[q][0]; bw1 = wq[q][1]; bw2 = wq[q][2]; bw3 = wq[q][3];
            bm = mq[q];
        }
    }
    unsigned long long gbest = best;
#pragma unroll
    for (int off = 32; off > 0; off >>= 1) {
        unsigned long long other = __shfl_xor(gbest, off);
        gbest = other > gbest ? other : gbest;
    }

    if (alive) {
        int wo = 1023 - (int)(gbest & 0xFFFFull);
        if ((wo & 63) == lane && best == gbest) {
            int nsp = __popc(bm & 0x7FFFu);
            int e2 = 15 - nsp;
            e2 = e2 < 0 ? 0 : (e2 > 14 ? 14 : e2);
            float vv = 0.f;
#pragma unroll
            for (int k = 0; k < 4; k++) {
                float wk = (k == 0) ? bw0 : (k == 1) ? bw1 : (k == 2) ? bw2 : bw3;
                vv += (e2 >= tj[k]) ? wk : 0.f;
            }
            vv = (vv < THR2) ? 0.f : vv;
            vals[p] = vv; nsp_arr[p] = nsp; ow_arr[p] = wo;
            if (nsp > 0) atomicMax(bigbits, __float_as_uint(vv));
#pragma unroll
            for (int t = 0; t < T_; t++) {
                if ((bm >> t) & 1u) {
                    float vt = 0.f;
                    vt += (t >= tj[0]) ? bw0 : 0.f;
                    vt += (t >= tj[1]) ? bw1 : 0.f;
                    vt += (t >= tj[2]) ? bw2 : 0.f;
                    vt += (t >= tj[3]) ? bw3 : 0.f;
                    int idx = ((t * C2_ + wo) * H2 + y2) * H2 + x2;
                    v_out[idx] = vt;
                    s_out[idx] = 1.0f;
                }
            }
        }
    } else if (lane == 0) {
        vals[p] = 0.f; nsp_arr[p] = 0; ow_arr[p] = 0;
    }
}

// ---------------------------------------------------------------------------
// K4: greedy k-WTA (8 winners), 1024-thread block (validated; TLP hides LDS
// latency — the 64-thread variant was 80x slower). Exact reference tie-break.
__global__ __launch_bounds__(1024) void k4_kwta(const float* __restrict__ vals,
                                                const int* __restrict__ nsp,
                                                const int* __restrict__ ow,
                                                const unsigned int* __restrict__ bigbits,
                                                float* __restrict__ wout) {
    __shared__ float tot[NPOS];
    __shared__ short och[NPOS];
    __shared__ unsigned long long amax;
    int tid = threadIdx.x;
    float big = __uint_as_float(*bigbits) * 15.0f;

    for (int p = tid; p < NPOS; p += 1024) {
        int n = nsp[p];
        tot[p] = (n > 0) ? (float)n * (vals[p] + big) : 0.0f;
        och[p] = (short)ow[p];
    }
    if (tid == 0) amax = 0ull;
    __syncthreads();

    for (int it = 0; it < 8; it++) {
        unsigned long long best = 0ull;
        for (int p = tid; p < NPOS; p += 1024) {
            float tv = tot[p];
            if (tv > 0.0f) {
                unsigned int k = (unsigned)och[p] * (unsigned)NPOS + (unsigned)p;
                unsigned long long pk =
                    ((unsigned long long)__float_as_uint(tv) << 21) |
                    (unsigned long long)(0x1FFFFFu - k);
                best = pk > best ? pk : best;
            }
        }
#pragma unroll
        for (int off = 32; off > 0; off >>= 1) {
            unsigned long long other = __shfl_xor(best, off);
            best = other > best ? other : best;
        }
        if ((tid & 63) == 0) atomicMax(&amax, best);
        __syncthreads();
        unsigned long long mx = amax;
        __syncthreads();
        if (tid == 0) amax = 0ull;

        if (mx == 0ull) {
            if (tid == 0) {
                wout[it * 3 + 0] = -1.f; wout[it * 3 + 1] = -1.f; wout[it * 3 + 2] = -1.f;
            }
        } else {
            unsigned int k = 0x1FFFFFu - (unsigned)(mx & 0x1FFFFFull);
            int f = (int)(k / NPOS), pp = (int)(k % NPOS);
            int r = pp / H2, col = pp % H2;
            if (tid == 0) {
                wout[it * 3 + 0] = (float)f; wout[it * 3 + 1] = (float)r; wout[it * 3 + 2] = (float)col;
            }
            for (int p = tid; p < NPOS; p += 1024) {
                int pr = p / H2, pc = p % H2;
                bool kill = (och[p] == (short)f) ||
                            (pr >= r - 1 && pr <= r + 1 && pc >= col - 1 && pc <= col + 1);
                if (kill) tot[p] = 0.0f;
            }
        }
        __syncthreads();
    }
}

// ---------------------------------------------------------------------------
extern "C" void kernel_launch(void* const* d_in, const int* in_sizes, int n_in,
                              void* d_out, int out_size, void* d_ws, size_t ws_size,
                              hipStream_t stream) {
    const float* inp = (const float*)d_in[0];
    const float* w1  = (const float*)d_in[1];
    const float* w2  = (const float*)d_in[2];

    float* out = (float*)d_out;
    float* s_out = out;                    // [15,256,82,82]
    float* v_out = out + (size_t)NS;       // [15,256,82,82]
    float* wnr   = out + 2 * (size_t)NS;   // [8,3] as floats

    size_t need = (size_t)15 << 20;
    bool big_ws = ws_size >= need;
    char* scratch = big_ws ? (char*)d_ws
                           : (char*)d_out + (size_t)NS * sizeof(float);
    unsigned int* maskg = (unsigned int*)scratch;                   // 7.68 MB
    unsigned char* fst1 = (unsigned char*)(scratch + (8 << 20));    // 3.27 MB
    float* w1T = (float*)(scratch + (12 << 20));                    // 76.8 KB
    float* w2T = (float*)(scratch + (13 << 20));                    // 512 KB
    char* smol = big_ws ? (char*)d_ws + (14 << 20) : (char*)d_ws;
    unsigned char* win_t  = (unsigned char*)smol;
    unsigned char* win_ch = (unsigned char*)smol + 8192;
    float* vals = (float*)(smol + 16384);
    int*   nsp  = (int*)(smol + 49152);
    int*   ow   = (int*)(smol + 81920);
    unsigned int* bigbits = (unsigned int*)(smol + 114688);

    size_t n16 = (size_t)out_size / 4;     // out_size divisible by 4
    size_t nA  = big_ws ? n16 / 4 : 0;     // k_mega fills [0,nA), k1 fills [nA,n16)
    int nf1 = big_ws ? NF1 : 0;
    int nf2 = big_ws ? NF2 : 0;

    hipLaunchKernelGGL(k_mega, dim3(687 + nf1), dim3(256), 0, stream,
                       inp, w1, w2, maskg, w1T, w2T, bigbits, (uint4*)d_out, nA, nf1);
    hipLaunchKernelGGL(k1_main, dim3(6400 + nf2), dim3(256), 0, stream,
                       maskg, w1T, fst1, (uint4*)d_out, nA, n16, nf2);
    hipLaunchKernelGGL(k2_pool, dim3((HP * HP + 3) / 4), dim3(256), 0, stream,
                       fst1, win_t, win_ch);
    if (!big_ws)
        hipLaunchKernelGGL(kz_fill, dim3(4096), dim3(256), 0, stream,
                           (uint4*)d_out, n16, bigbits);
    hipLaunchKernelGGL(k3_conv2, dim3(NPOS / 4), dim3(256), 0, stream,
                       win_t, win_ch, w2T, s_out, v_out, vals, nsp, ow, bigbits);
    hipLaunchKernelGGL(k4_kwta, dim3(1), dim3(1024), 0, stream, vals, nsp, ow, bigbits, wnr);
}

// Round 11
// 195.294 us; speedup vs baseline: 2.4344x; 1.0203x over previous
//
#include <hip/hip_runtime.h>

#define T_ 15
#define CIN 6
#define H0 160
#define W0 160
#define C1_ 128
#define C2_ 256
#define HP 83            // padded pooled grid (83x83)
#define H2 82            // conv2 output (82x82)
#define NPIX (H0*W0)     // 25600
#define NIN (CIN*NPIX)   // 153600
#define NPOS (H2*H2)     // 6724
#define NS (T_*C2_*NPOS) // 25,820,160 elements per s/v output
#define THR1 10.0f
#define THR2 1.0f

// ---------------------------------------------------------------------------
// MEGA prep kernel (prep only; fill moved into k1's compute blocks).
//   b in [0,100):   per-tile tap sort -> time-bitmasks maskg[t][w][pix]
//   b in [100,175): w1T[j][c] transpose (+ b==100 zeroes bigbits)
//   b in [175,687): w2T[k][cc][o] transpose
__global__ __launch_bounds__(256) void k_mega(const float* __restrict__ inp,
                                              const float* __restrict__ w1,
                                              const float* __restrict__ w2,
                                              unsigned int* __restrict__ maskg,
                                              float* __restrict__ w1T,
                                              float* __restrict__ w2T,
                                              unsigned int* __restrict__ bigbits) {
    __shared__ unsigned char tft[CIN * 20 * 20]; // 2400 B tf tile (with halo)
    __shared__ int cnt[16 * 256];                // per-lane bitmask columns
    int b = blockIdx.x;
    int tid = threadIdx.x;

    if (b < 100) {
        // ---- tap sort tile ----
        int ty0 = (b / 10) * 16, tx0 = (b % 10) * 16;
        for (int i = tid; i < CIN * 400; i += 256) {
            int ci = i / 400, rem = i % 400;
            int ly = rem / 20, lx = rem % 20;
            int y = ty0 + ly - 2, x = tx0 + lx - 2;
            unsigned char tv = 15;
            if ((unsigned)y < (unsigned)H0 && (unsigned)x < (unsigned)W0) {
                float c = 0.f;
                int base = ci * NPIX + y * W0 + x;
#pragma unroll
                for (int t = 0; t < T_; t++) c += inp[(size_t)t * NIN + base];
                tv = (unsigned char)(15 - (int)(c + 0.5f));
            }
            tft[i] = tv;
        }
        __syncthreads();

        int tyl = tid >> 4, txl = tid & 15;
        int pix = (ty0 + tyl) * W0 + (tx0 + txl);
        int* col = cnt + tid;   // private column: bank = tid%32, conflict-free

#pragma unroll
        for (int w = 0; w < 5; w++) {
            int j0 = w * 32, j1 = (w == 4) ? 150 : (j0 + 32);
#pragma unroll
            for (int q = 0; q < 16; q++) col[q * 256] = 0;
#pragma unroll 32
            for (int j = j0; j < j1; j++) {
                int ci = j / 25, r = j % 25, ky = r / 5, kx = r % 5;
                int tfv = tft[ci * 400 + (tyl + ky) * 20 + (txl + kx)];
                col[tfv * 256] |= 1u << (j & 31);   // slot 15 = trash
            }
#pragma unroll
            for (int t = 0; t < 15; t++)
                maskg[(size_t)(t * 5 + w) * NPIX + pix] = (unsigned)col[t * 256];
        }
    } else if (b < 175) {
        // ---- w1T[j][c] = w1[c][j] ----
        if (b == 100 && tid == 0) *bigbits = 0u;
        int idx = (b - 100) * 256 + tid;      // < 19200
        int j = idx >> 7, c = idx & 127;
        w1T[idx] = w1[c * 150 + j];
    } else {
        // ---- w2T[k][cc][o] = w2[o][cc][k] ----
        int idx = (b - 175) * 256 + tid;      // < 131072
        int o = idx & 255, kcc = idx >> 8;
        int cc = kcc & 127, k = kcc >> 7;
        w2T[idx] = w2[o * 512 + cc * 4 + k];
    }
}

// ---------------------------------------------------------------------------
// K1: wave = ONE pixel, lane = channel pair (2c,2c+1). NEW (r10): each compute
// block ALSO zero-fills its 32KB slice of d_out, stores issued BEFORE the
// compute — they drain in the write pipe under the latency-bound conv1 chain
// (fire-and-forget; no waitcnt until kernel end). This replaces the fill-only
// blocks that serialized as a pure-fill tail behind the compute blocks.
// Taps consumed bucket-by-bucket via time-bitmasks (ctz = j-ascending within
// bucket -> exact same fp32 summation tree as the validated kernel).
__global__ __launch_bounds__(256) void k1_main(const unsigned int* __restrict__ maskg,
                                               const float* __restrict__ w1T,
                                               unsigned char* __restrict__ fst1,
                                               uint4* __restrict__ fill_dst,
                                               size_t n16) {
    int b = blockIdx.x;
    int tid = threadIdx.x;

    if (n16) {  // big_ws path: fill my slice of d_out (zeros)
        size_t per = (n16 + 6399) / 6400;              // 2018 uint4 per block
        size_t i = (size_t)b * per + tid;
        size_t e = (size_t)(b + 1) * per;
        if (e > n16) e = n16;
        uint4 z = make_uint4(0u, 0u, 0u, 0u);
        for (; i < e; i += 256) fill_dst[i] = z;
    }

    int pix = b * 4 + (tid >> 6);
    int lane = tid & 63;
    const float* wb = w1T + 2 * lane;

    float v0 = 0.f, v1 = 0.f;
    int f0 = 15, f1 = 15;
    for (int t = 0; t < 15; ++t) {
        float b0 = 0.f, b1 = 0.f;
#pragma unroll
        for (int w = 0; w < 5; ++w) {
            unsigned int m = maskg[(size_t)(t * 5 + w) * NPIX + pix]; // wave-uniform
            int base = w * 32;
            while (m) {
                int j = base + __builtin_ctz(m);
                m &= m - 1;
                float2 ww = *(const float2*)(wb + j * C1_); // coalesced 512B
                b0 += ww.x; b1 += ww.y;
            }
        }
        v0 += b0; v1 += b1;
        f0 = (f0 == 15 && v0 >= THR1) ? t : f0;
        f1 = (f1 == 15 && v1 >= THR1) ? t : f1;
        if (__all((f0 < 15) & (f1 < 15))) break;
    }
    *(uchar2*)(fst1 + (size_t)pix * C1_ + 2 * lane) =
        make_uchar2((unsigned char)f0, (unsigned char)f1);
}

// ---------------------------------------------------------------------------
// K2: wave = one padded-grid position, lane = channel pair. pool-min over the
// 2x2 window of fst1[pix][ch], then winner = min (tf<<8 | ch) across channels.
__global__ __launch_bounds__(256) void k2_pool(const unsigned char* __restrict__ fst1,
                                               unsigned char* __restrict__ win_t,
                                               unsigned char* __restrict__ win_ch) {
    int pos = blockIdx.x * 4 + (threadIdx.x >> 6);
    int lane = threadIdx.x & 63;
    if (pos >= HP * HP) return;
    int py = pos / HP, px = pos % HP;
    if (py == 0 || py == HP - 1 || px == 0 || px == HP - 1) {
        if (lane == 0) { win_t[pos] = 15; win_ch[pos] = 0; }
        return;
    }
    int y0 = 2 * py - 3, x0 = 2 * px - 3;
    int m0 = 15, m1 = 15;
#pragma unroll
    for (int dy = 0; dy < 2; dy++) {
        int y = y0 + dy;
        if ((unsigned)y < (unsigned)H0) {
#pragma unroll
            for (int dx = 0; dx < 2; dx++) {
                int x = x0 + dx;
                if ((unsigned)x < (unsigned)W0) {
                    uchar2 f = *(const uchar2*)(fst1 + (size_t)(y * W0 + x) * C1_ + 2 * lane);
                    m0 = f.x < m0 ? f.x : m0;
                    m1 = f.y < m1 ? f.y : m1;
                }
            }
        }
    }
    int k0 = (m0 << 8) | (2 * lane);
    int k1 = (m1 << 8) | (2 * lane + 1);
    int key = k0 < k1 ? k0 : k1;
#pragma unroll
    for (int off = 32; off > 0; off >>= 1) {
        int other = __shfl_xor(key, off);
        key = other < key ? other : key;
    }
    if (lane == 0) {
        win_t[pos] = (unsigned char)(key >> 8);
        win_ch[pos] = (unsigned char)(key & 255);
    }
}

// ---------------------------------------------------------------------------
// KZ: fallback full zero-fill (only if ws_size is unexpectedly small).
__global__ __launch_bounds__(256) void kz_fill(uint4* __restrict__ dst, size_t n16,
                                               unsigned int* __restrict__ bigbits) {
    size_t stride = (size_t)gridDim.x * 256;
    uint4 z = make_uint4(0u, 0u, 0u, 0u);
    for (size_t i = (size_t)blockIdx.x * 256 + threadIdx.x; i < n16; i += stride)
        dst[i] = z;
    if (blockIdx.x == 0 && threadIdx.x == 0) *bigbits = 0u;
}

// ---------------------------------------------------------------------------
// K3: wave = one output position, lane = 4 channels (q*64+lane). No LDS, no
// barriers; register state + shfl butterflies. Arithmetic bit-identical to
// the validated block version.
__global__ __launch_bounds__(256) void k3_conv2(const unsigned char* __restrict__ win_t,
                                                const unsigned char* __restrict__ win_ch,
                                                const float* __restrict__ w2T,
                                                float* __restrict__ s_out,
                                                float* __restrict__ v_out,
                                                float* __restrict__ vals,
                                                int* __restrict__ nsp_arr,
                                                int* __restrict__ ow_arr,
                                                unsigned int* __restrict__ bigbits) {
    int p = blockIdx.x * 4 + (threadIdx.x >> 6);   // grid exact: 1681*4 = NPOS
    int lane = threadIdx.x & 63;
    int y2 = p / H2, x2 = p % H2;

    int tj[4]; int ccv[4];
#pragma unroll
    for (int k = 0; k < 4; k++) {
        int dy = k >> 1, dx = k & 1;
        int pi = (y2 + dy) * HP + (x2 + dx);
        tj[k] = win_t[pi];          // wave-uniform loads (broadcast)
        ccv[k] = win_ch[pi];
    }

    float wq[4][4];
    unsigned int mq[4];
    unsigned int lane_or = 0u;
#pragma unroll
    for (int q = 0; q < 4; q++) {
        int ch = q * 64 + lane;
#pragma unroll
        for (int k = 0; k < 4; k++)
            wq[q][k] = (tj[k] < 15) ? w2T[(k * C1_ + ccv[k]) * 256 + ch] : 0.0f;
        unsigned int m = 0u;
#pragma unroll
        for (int t = 0; t < T_; t++) {
            float v = 0.f;
#pragma unroll
            for (int k = 0; k < 4; k++) v += (t >= tj[k]) ? wq[q][k] : 0.f;
            m |= (v >= THR2) ? (1u << t) : 0u;   // zz>0 <=> v>=1
        }
        mq[q] = m;
        lane_or |= m;
    }

#pragma unroll
    for (int off = 32; off > 0; off >>= 1) lane_or |= __shfl_xor(lane_or, off);
    unsigned int om = lane_or;
    int count = __popc(om & 0x7FFFu);
    int earliest = 15 - count;
    earliest = earliest < 0 ? 0 : (earliest > 14 ? 14 : earliest);
    int alive = (om >> 14) & 1;

    unsigned long long best = 0ull;
    float bw0 = 0.f, bw1 = 0.f, bw2 = 0.f, bw3 = 0.f;
    unsigned int bm = 0u;
#pragma unroll
    for (int q = 0; q < 4; q++) {
        int ch = q * 64 + lane;
        float v = 0.f;
#pragma unroll
        for (int k = 0; k < 4; k++) v += (earliest >= tj[k]) ? wq[q][k] : 0.f;
        float zval = (v < THR2) ? 0.f : v;
        unsigned long long key =
            ((unsigned long long)__float_as_uint(zval) << 16) |
            (unsigned long long)(1023 - ch);
        if (key > best) {
            best = key;
            bw0 = wq[q][0]; bw1 = wq[q][1]; bw2 = wq[q][2]; bw3 = wq[q][3];
            bm = mq[q];
        }
    }
    unsigned long long gbest = best;
#pragma unroll
    for (int off = 32; off > 0; off >>= 1) {
        unsigned long long other = __shfl_xor(gbest, off);
        gbest = other > gbest ? other : gbest;
    }

    if (alive) {
        int wo = 1023 - (int)(gbest & 0xFFFFull);
        if ((wo & 63) == lane && best == gbest) {
            int nsp = __popc(bm & 0x7FFFu);
            int e2 = 15 - nsp;
            e2 = e2 < 0 ? 0 : (e2 > 14 ? 14 : e2);
            float vv = 0.f;
#pragma unroll
            for (int k = 0; k < 4; k++) {
                float wk = (k == 0) ? bw0 : (k == 1) ? bw1 : (k == 2) ? bw2 : bw3;
                vv += (e2 >= tj[k]) ? wk : 0.f;
            }
            vv = (vv < THR2) ? 0.f : vv;
            vals[p] = vv; nsp_arr[p] = nsp; ow_arr[p] = wo;
            if (nsp > 0) atomicMax(bigbits, __float_as_uint(vv));
#pragma unroll
            for (int t = 0; t < T_; t++) {
                if ((bm >> t) & 1u) {
                    float vt = 0.f;
                    vt += (t >= tj[0]) ? bw0 : 0.f;
                    vt += (t >= tj[1]) ? bw1 : 0.f;
                    vt += (t >= tj[2]) ? bw2 : 0.f;
                    vt += (t >= tj[3]) ? bw3 : 0.f;
                    int idx = ((t * C2_ + wo) * H2 + y2) * H2 + x2;
                    v_out[idx] = vt;
                    s_out[idx] = 1.0f;
                }
            }
        }
    } else if (lane == 0) {
        vals[p] = 0.f; nsp_arr[p] = 0; ow_arr[p] = 0;
    }
}

// ---------------------------------------------------------------------------
// K4: greedy k-WTA (8 winners), 1024-thread block (validated; TLP hides LDS
// latency — the 64-thread variant was 80x slower). Exact reference tie-break.
__global__ __launch_bounds__(1024) void k4_kwta(const float* __restrict__ vals,
                                                const int* __restrict__ nsp,
                                                const int* __restrict__ ow,
                                                const unsigned int* __restrict__ bigbits,
                                                float* __restrict__ wout) {
    __shared__ float tot[NPOS];
    __shared__ short och[NPOS];
    __shared__ unsigned long long amax;
    int tid = threadIdx.x;
    float big = __uint_as_float(*bigbits) * 15.0f;

    for (int p = tid; p < NPOS; p += 1024) {
        int n = nsp[p];
        tot[p] = (n > 0) ? (float)n * (vals[p] + big) : 0.0f;
        och[p] = (short)ow[p];
    }
    if (tid == 0) amax = 0ull;
    __syncthreads();

    for (int it = 0; it < 8; it++) {
        unsigned long long best = 0ull;
        for (int p = tid; p < NPOS; p += 1024) {
            float tv = tot[p];
            if (tv > 0.0f) {
                unsigned int k = (unsigned)och[p] * (unsigned)NPOS + (unsigned)p;
                unsigned long long pk =
                    ((unsigned long long)__float_as_uint(tv) << 21) |
                    (unsigned long long)(0x1FFFFFu - k);
                best = pk > best ? pk : best;
            }
        }
#pragma unroll
        for (int off = 32; off > 0; off >>= 1) {
            unsigned long long other = __shfl_xor(best, off);
            best = other > best ? other : best;
        }
        if ((tid & 63) == 0) atomicMax(&amax, best);
        __syncthreads();
        unsigned long long mx = amax;
        __syncthreads();
        if (tid == 0) amax = 0ull;

        if (mx == 0ull) {
            if (tid == 0) {
                wout[it * 3 + 0] = -1.f; wout[it * 3 + 1] = -1.f; wout[it * 3 + 2] = -1.f;
            }
        } else {
            unsigned int k = 0x1FFFFFu - (unsigned)(mx & 0x1FFFFFull);
            int f = (int)(k / NPOS), pp = (int)(k % NPOS);
            int r = pp / H2, col = pp % H2;
            if (tid == 0) {
                wout[it * 3 + 0] = (float)f; wout[it * 3 + 1] = (float)r; wout[it * 3 + 2] = (float)col;
            }
            for (int p = tid; p < NPOS; p += 1024) {
                int pr = p / H2, pc = p % H2;
                bool kill = (och[p] == (short)f) ||
                            (pr >= r - 1 && pr <= r + 1 && pc >= col - 1 && pc <= col + 1);
                if (kill) tot[p] = 0.0f;
            }
        }
        __syncthreads();
    }
}

// ---------------------------------------------------------------------------
extern "C" void kernel_launch(void* const* d_in, const int* in_sizes, int n_in,
                              void* d_out, int out_size, void* d_ws, size_t ws_size,
                              hipStream_t stream) {
    const float* inp = (const float*)d_in[0];
    const float* w1  = (const float*)d_in[1];
    const float* w2  = (const float*)d_in[2];

    float* out = (float*)d_out;
    float* s_out = out;                    // [15,256,82,82]
    float* v_out = out + (size_t)NS;       // [15,256,82,82]
    float* wnr   = out + 2 * (size_t)NS;   // [8,3] as floats

    size_t need = (size_t)15 << 20;
    bool big_ws = ws_size >= need;
    char* scratch = big_ws ? (char*)d_ws
                           : (char*)d_out + (size_t)NS * sizeof(float);
    unsigned int* maskg = (unsigned int*)scratch;                   // 7.68 MB
    unsigned char* fst1 = (unsigned char*)(scratch + (8 << 20));    // 3.27 MB
    float* w1T = (float*)(scratch + (12 << 20));                    // 76.8 KB
    float* w2T = (float*)(scratch + (13 << 20));                    // 512 KB
    char* smol = big_ws ? (char*)d_ws + (14 << 20) : (char*)d_ws;
    unsigned char* win_t  = (unsigned char*)smol;
    unsigned char* win_ch = (unsigned char*)smol + 8192;
    float* vals = (float*)(smol + 16384);
    int*   nsp  = (int*)(smol + 49152);
    int*   ow   = (int*)(smol + 81920);
    unsigned int* bigbits = (unsigned int*)(smol + 114688);

    size_t n16 = (size_t)out_size / 4;     // out_size divisible by 4
    size_t n16_k1 = big_ws ? n16 : 0;      // k1 fills d_out only when scratch is in d_ws

    hipLaunchKernelGGL(k_mega, dim3(687), dim3(256), 0, stream,
                       inp, w1, w2, maskg, w1T, w2T, bigbits);
    hipLaunchKernelGGL(k1_main, dim3(6400), dim3(256), 0, stream,
                       maskg, w1T, fst1, (uint4*)d_out, n16_k1);
    hipLaunchKernelGGL(k2_pool, dim3((HP * HP + 3) / 4), dim3(256), 0, stream,
                       fst1, win_t, win_ch);
    if (!big_ws)
        hipLaunchKernelGGL(kz_fill, dim3(4096), dim3(256), 0, stream,
                           (uint4*)d_out, n16, bigbits);
    hipLaunchKernelGGL(k3_conv2, dim3(NPOS / 4), dim3(256), 0, stream,
                       win_t, win_ch, w2T, s_out, v_out, vals, nsp, ow, bigbits);
    hipLaunchKernelGGL(k4_kwta, dim3(1), dim3(1024), 0, stream, vals, nsp, ow, bigbits, wnr);
}